// Round 12
// baseline (537.476 us; speedup 1.0000x reference)
//
#include <hip/hip_runtime.h>
#include <hip/hip_bf16.h>
#include <math.h>

#define HIDC 256
#define LSTR 40   // LDS row stride in ushorts: 80 B = 16B-aligned; stride=20 banks -> ~2-way (free per m136).

typedef short short8 __attribute__((ext_vector_type(8)));
typedef float f32x4 __attribute__((ext_vector_type(4)));

__device__ __forceinline__ ushort f2bf_rne(float f) {
    uint u = __float_as_uint(f);
    u += 0x7FFF + ((u >> 16) & 1);
    return (ushort)(u >> 16);
}
__device__ __forceinline__ float bf2f(ushort h) {
    return __uint_as_float(((uint)h) << 16);
}
__device__ __forceinline__ f32x4 MF(short8 a, short8 b, f32x4 c) {
    return __builtin_amdgcn_mfma_f32_16x16x32_bf16(a, b, c, 0, 0, 0);
}

// ---------------- small utility kernels ----------------

__global__ void fill_i_kernel(int* __restrict__ p, int v, int n) {
    int i = blockIdx.x * 256 + threadIdx.x;
    if (i < n) p[i] = v;
}

__global__ void deg_kernel(const int* __restrict__ dst, int* __restrict__ deg, int E) {
    int e = blockIdx.x * 256 + threadIdx.x;
    if (e < E) atomicAdd(&deg[dst[e]], 1);
}

// ---------------- 3-kernel exclusive scan (scan_a also emits dinv) ----------------

__device__ __forceinline__ int block_incl_scan(int v, int tid) {
#pragma unroll
    for (int off = 1; off < 64; off <<= 1) {
        int t = __shfl_up(v, off);
        if ((tid & 63) >= off) v += t;
    }
    __shared__ int wt[4];
    if ((tid & 63) == 63) wt[tid >> 6] = v;
    __syncthreads();
    int wid = tid >> 6;
    for (int w = 0; w < wid; w++) v += wt[w];
    __syncthreads();
    return v;
}

__global__ void scan_a_kernel(const int* __restrict__ deg, int* __restrict__ row_start,
                              int* __restrict__ blocksum, float* __restrict__ dinv, int N) {
    int tid = threadIdx.x;
    int i = blockIdx.x * 256 + tid;
    int v = (i < N) ? deg[i] : 0;
    int incl = block_incl_scan(v, tid);
    if (i < N) {
        row_start[i + 1] = incl;
        dinv[i] = rsqrtf((float)(v + 1));   // +1 = self-loop (folded rsqrt_kernel)
    }
    if (tid == 255) blocksum[blockIdx.x] = incl;
}

__global__ void scan_b_kernel(int* __restrict__ blocksum, int nb) {
    int tid = threadIdx.x;
    int v = (tid < nb) ? blocksum[tid] : 0;
    int incl = block_incl_scan(v, tid);
    if (tid < nb) blocksum[tid] = incl;
}

__global__ void scan_c_kernel(int* __restrict__ row_start, int* __restrict__ cursor,
                              const int* __restrict__ blocksum, int N) {
    int b = blockIdx.x;
    int i = b * 256 + threadIdx.x;
    int add = (b > 0) ? blocksum[b - 1] : 0;
    if (i < N) {
        int v = row_start[i + 1] + add;
        row_start[i + 1] = v;
        cursor[i + 1] = v;
    }
    if (b == 0 && threadIdx.x == 0) { row_start[0] = 0; cursor[0] = 0; }
}

__global__ void scatter_kernel(const int* __restrict__ src, const int* __restrict__ dst,
                               const float* __restrict__ dinv, int* __restrict__ cursor,
                               int* __restrict__ csr_src, float* __restrict__ csr_w, int E) {
    int e = blockIdx.x * 256 + threadIdx.x;
    if (e < E) {
        int s = src[e], d = dst[e];
        int pos = atomicAdd(&cursor[d], 1);
        csr_src[pos] = s;
        csr_w[pos] = dinv[s] * dinv[d];
    }
}

// ---------------- weight prep: single merged kernel (3 launches -> 1) ----------------
// Bt[n][k] = bf16(B[k][n]); gate: rows 0..255 <- gWw, 256..511 <- gUw, hi/lo split, [n][512k]

__global__ void prep_all_kernel(const float* __restrict__ W1, const float* __restrict__ W2,
                                const float* __restrict__ gWw, const float* __restrict__ gUw,
                                ushort* __restrict__ Bt1, ushort* __restrict__ Bt2,
                                ushort* __restrict__ Bth, ushort* __restrict__ Btl) {
    int n = blockIdx.x, k = threadIdx.x;
    Bt1[n * 256 + k] = f2bf_rne(W1[k * 256 + n]);
    Bt2[n * 256 + k] = f2bf_rne(W2[k * 256 + n]);
    float v1 = gWw[k * 256 + n];
    uint u1 = __float_as_uint(v1);
    Bth[n * 512 + k] = (ushort)(u1 >> 16);
    Btl[n * 512 + k] = f2bf_rne(v1 - __uint_as_float(u1 & 0xFFFF0000u));
    float v2 = gUw[k * 256 + n];
    uint u2 = __float_as_uint(v2);
    Bth[n * 512 + 256 + k] = (ushort)(u2 >> 16);
    Btl[n * 512 + 256 + k] = f2bf_rne(v2 - __uint_as_float(u2 & 0xFFFF0000u));
}

// ---------------- MFMA GEMM conv1: 128x128 tile, dbuf LDS, SINGLE barrier per K-step ----------------
// r9-proven pipeline pattern: prefetch raw(kq+1)->regs, ds_read+MFMA(kq) hides load latency,
// convert+ds_write(kq+1)->buf^1, ONE barrier. Numerics identical to r2/r10 (same RNE, same MFMA order).

__global__ __launch_bounds__(256, 3) void gemm_bf16_kernel(
    const float* __restrict__ A, const ushort* __restrict__ Bt,  // Bt: [256n][256k] bf16
    ushort* __restrict__ C, int M)
{
    __shared__ __align__(16) ushort As[2][128 * LSTR];
    __shared__ __align__(16) ushort Bs[2][128 * LSTR];
    const int tl = threadIdx.x;
    const int lane = tl & 63, wave = tl >> 6;
    const int wm = (wave & 1) * 64, wn = (wave >> 1) * 64;
    const int bm = blockIdx.x * 128, bn = blockIdx.y * 128;

    const int ar  = tl >> 1;          // stage row
    const int akq = (tl & 1) * 16;    // stage k base (16 elems)
    const bool aok = (bm + ar) < M;
    const float*  apb = A  + (size_t)(bm + ar) * HIDC + akq;
    const ushort* bpb = Bt + (size_t)(bn + ar) * 256 + akq;

    f32x4 acc[4][4] = {};
    const float4 z4 = make_float4(0.f, 0.f, 0.f, 0.f);
    float4 ra[4]; uint4 rb0, rb1;

    // prologue: raw load kq=0, stage into buf0
#pragma unroll
    for (int j = 0; j < 4; j++) ra[j] = aok ? *(const float4*)(apb + 4 * j) : z4;
    rb0 = *(const uint4*)(bpb);
    rb1 = *(const uint4*)(bpb + 8);
#pragma unroll
    for (int j = 0; j < 4; j++) {
        ushort4 h;
        h.x = f2bf_rne(ra[j].x); h.y = f2bf_rne(ra[j].y);
        h.z = f2bf_rne(ra[j].z); h.w = f2bf_rne(ra[j].w);
        *(ushort4*)&As[0][ar * LSTR + akq + 4 * j] = h;
    }
    *(uint4*)&Bs[0][ar * LSTR + akq]     = rb0;
    *(uint4*)&Bs[0][ar * LSTR + akq + 8] = rb1;
    __syncthreads();

    const int fr = lane & 15, koff = (lane >> 4) * 8;
    int cur = 0;
#pragma unroll
    for (int kq = 0; kq < 8; kq++) {
        if (kq + 1 < 8) {   // 1. prefetch raw kq+1 (latency hides under MFMAs below)
#pragma unroll
            for (int j = 0; j < 4; j++)
                ra[j] = aok ? *(const float4*)(apb + (kq + 1) * 32 + 4 * j) : z4;
            rb0 = *(const uint4*)(bpb + (kq + 1) * 32);
            rb1 = *(const uint4*)(bpb + (kq + 1) * 32 + 8);
        }
        short8 af[4], bfv[4];                 // 2. frags from LDS[cur]
#pragma unroll
        for (int t = 0; t < 4; t++) {
            af[t]  = *(const short8*)&As[cur][(wm + t * 16 + fr) * LSTR + koff];
            bfv[t] = *(const short8*)&Bs[cur][(wn + t * 16 + fr) * LSTR + koff];
        }
#pragma unroll
        for (int mt = 0; mt < 4; mt++)        // 3. MFMA
#pragma unroll
            for (int nt = 0; nt < 4; nt++)
                acc[mt][nt] = MF(af[mt], bfv[nt], acc[mt][nt]);
        if (kq + 1 < 8) {                     // 4. stage kq+1 into buf^1, 5. ONE barrier
#pragma unroll
            for (int j = 0; j < 4; j++) {
                ushort4 h;
                h.x = f2bf_rne(ra[j].x); h.y = f2bf_rne(ra[j].y);
                h.z = f2bf_rne(ra[j].z); h.w = f2bf_rne(ra[j].w);
                *(ushort4*)&As[cur ^ 1][ar * LSTR + akq + 4 * j] = h;
            }
            *(uint4*)&Bs[cur ^ 1][ar * LSTR + akq]     = rb0;
            *(uint4*)&Bs[cur ^ 1][ar * LSTR + akq + 8] = rb1;
            __syncthreads();
            cur ^= 1;
        }
    }

    // epilogue: C/D layout col=lane&15, row=(lane>>4)*4+reg  [m89-verified]
    const int row4 = (lane >> 4) * 4, coln = lane & 15;
#pragma unroll
    for (int mt = 0; mt < 4; mt++)
#pragma unroll
        for (int r = 0; r < 4; r++) {
            int m = bm + wm + mt * 16 + row4 + r;
            if (m < M) {
#pragma unroll
                for (int nt = 0; nt < 4; nt++) {
                    int n = bn + wn + nt * 16 + coln;
                    C[(size_t)m * HIDC + n] = f2bf_rne(acc[mt][nt][r]);
                }
            }
        }
}

// ---------------- conv2: A already bf16, same single-barrier dbuf pipeline ----------------

__global__ __launch_bounds__(256, 3) void gemm_bf16A_kernel(
    const ushort* __restrict__ A, const ushort* __restrict__ Bt,  // A: [M][256] bf16
    ushort* __restrict__ C, int M)
{
    __shared__ __align__(16) ushort As[2][128 * LSTR];
    __shared__ __align__(16) ushort Bs[2][128 * LSTR];
    const int tl = threadIdx.x;
    const int lane = tl & 63, wave = tl >> 6;
    const int wm = (wave & 1) * 64, wn = (wave >> 1) * 64;
    const int bm = blockIdx.x * 128, bn = blockIdx.y * 128;

    const int ar  = tl >> 1;
    const int akq = (tl & 1) * 16;
    const bool aok = (bm + ar) < M;
    const ushort* apb = A  + (size_t)(bm + ar) * HIDC + akq;
    const ushort* bpb = Bt + (size_t)(bn + ar) * 256 + akq;

    f32x4 acc[4][4] = {};
    const uint4 z = make_uint4(0u, 0u, 0u, 0u);
    uint4 ua0, ua1, rb0, rb1;

    // prologue
    ua0 = aok ? *(const uint4*)(apb)     : z;
    ua1 = aok ? *(const uint4*)(apb + 8) : z;
    rb0 = *(const uint4*)(bpb);
    rb1 = *(const uint4*)(bpb + 8);
    *(uint4*)&As[0][ar * LSTR + akq]     = ua0;
    *(uint4*)&As[0][ar * LSTR + akq + 8] = ua1;
    *(uint4*)&Bs[0][ar * LSTR + akq]     = rb0;
    *(uint4*)&Bs[0][ar * LSTR + akq + 8] = rb1;
    __syncthreads();

    const int fr = lane & 15, koff = (lane >> 4) * 8;
    int cur = 0;
#pragma unroll
    for (int kq = 0; kq < 8; kq++) {
        if (kq + 1 < 8) {
            ua0 = aok ? *(const uint4*)(apb + (kq + 1) * 32)     : z;
            ua1 = aok ? *(const uint4*)(apb + (kq + 1) * 32 + 8) : z;
            rb0 = *(const uint4*)(bpb + (kq + 1) * 32);
            rb1 = *(const uint4*)(bpb + (kq + 1) * 32 + 8);
        }
        short8 af[4], bfv[4];
#pragma unroll
        for (int t = 0; t < 4; t++) {
            af[t]  = *(const short8*)&As[cur][(wm + t * 16 + fr) * LSTR + koff];
            bfv[t] = *(const short8*)&Bs[cur][(wn + t * 16 + fr) * LSTR + koff];
        }
#pragma unroll
        for (int mt = 0; mt < 4; mt++)
#pragma unroll
            for (int nt = 0; nt < 4; nt++)
                acc[mt][nt] = MF(af[mt], bfv[nt], acc[mt][nt]);
        if (kq + 1 < 8) {
            *(uint4*)&As[cur ^ 1][ar * LSTR + akq]     = ua0;
            *(uint4*)&As[cur ^ 1][ar * LSTR + akq + 8] = ua1;
            *(uint4*)&Bs[cur ^ 1][ar * LSTR + akq]     = rb0;
            *(uint4*)&Bs[cur ^ 1][ar * LSTR + akq + 8] = rb1;
            __syncthreads();
            cur ^= 1;
        }
    }

    const int row4 = (lane >> 4) * 4, coln = lane & 15;
#pragma unroll
    for (int mt = 0; mt < 4; mt++)
#pragma unroll
        for (int r = 0; r < 4; r++) {
            int m = bm + wm + mt * 16 + row4 + r;
            if (m < M) {
#pragma unroll
                for (int nt = 0; nt < 4; nt++) {
                    int n = bn + wn + nt * 16 + coln;
                    C[(size_t)m * HIDC + n] = f2bf_rne(acc[mt][nt][r]);
                }
            }
        }
}

// ---------------- gate GEMM (r10-measured-best, UNCHANGED): BM=64, staged hi/lo A + hi/lo B ----------------

__global__ __launch_bounds__(256, 4) void gate_kernel(
    const float* __restrict__ ht, const float* __restrict__ prev,
    const ushort* __restrict__ Bth, const ushort* __restrict__ Btl,  // [256n][512k]
    const float* __restrict__ gWb, const float* __restrict__ gUb,
    float* __restrict__ out, int M)
{
    __shared__ __align__(16) ushort Ash[64 * LSTR];
    __shared__ __align__(16) ushort Asl[64 * LSTR];
    __shared__ __align__(16) ushort Bsh[128 * LSTR];
    __shared__ __align__(16) ushort Bsl[128 * LSTR];
    const int tl = threadIdx.x;
    const int lane = tl & 63, wave = tl >> 6;
    const int wm = (wave & 1) * 32, wn = (wave >> 1) * 64;
    const int bm = blockIdx.x * 64, bn = blockIdx.y * 128;

    const int arA = tl >> 2;          // 0..63
    const int kqA = (tl & 3) * 8;     // 8 floats
    const int arB = tl >> 1;
    const int kqB = (tl & 1) * 16;
    const bool aok = (bm + arA) < M;

    f32x4 acc[2][4] = {};

    for (int k0 = 0; k0 < 512; k0 += 32) {
        {   // A stage: hi/lo split from ht (k<256) or prev, 8 elems/thread
            const float* srcA = (k0 < 256) ? ht : prev;
            const float* ap = srcA + (size_t)(bm + arA) * HIDC + (k0 & 255) + kqA;
            float4 v0 = aok ? *(const float4*)(ap)     : make_float4(0.f, 0.f, 0.f, 0.f);
            float4 v1 = aok ? *(const float4*)(ap + 4) : make_float4(0.f, 0.f, 0.f, 0.f);
            float vv[8] = {v0.x, v0.y, v0.z, v0.w, v1.x, v1.y, v1.z, v1.w};
            ushort hp[8], lp[8];
#pragma unroll
            for (int q = 0; q < 8; q++) {
                uint u = __float_as_uint(vv[q]);
                hp[q] = (ushort)(u >> 16);
                lp[q] = f2bf_rne(vv[q] - __uint_as_float(u & 0xFFFF0000u));
            }
            *(ushort4*)&Ash[arA * LSTR + kqA]     = make_ushort4(hp[0], hp[1], hp[2], hp[3]);
            *(ushort4*)&Ash[arA * LSTR + kqA + 4] = make_ushort4(hp[4], hp[5], hp[6], hp[7]);
            *(ushort4*)&Asl[arA * LSTR + kqA]     = make_ushort4(lp[0], lp[1], lp[2], lp[3]);
            *(ushort4*)&Asl[arA * LSTR + kqA + 4] = make_ushort4(lp[4], lp[5], lp[6], lp[7]);
        }
        {   // B stage
            const ushort* bph = Bth + (size_t)(bn + arB) * 512 + k0 + kqB;
            const ushort* bpl = Btl + (size_t)(bn + arB) * 512 + k0 + kqB;
            *(uint4*)&Bsh[arB * LSTR + kqB]     = *(const uint4*)bph;
            *(uint4*)&Bsh[arB * LSTR + kqB + 8] = *(const uint4*)(bph + 8);
            *(uint4*)&Bsl[arB * LSTR + kqB]     = *(const uint4*)bpl;
            *(uint4*)&Bsl[arB * LSTR + kqB + 8] = *(const uint4*)(bpl + 8);
        }
        __syncthreads();
        const int fr = lane & 15, koff = (lane >> 4) * 8;
        short8 afh[2], afl[2], bfh[4], bfl[4];
#pragma unroll
        for (int t = 0; t < 2; t++) {
            afh[t] = *(const short8*)&Ash[(wm + t * 16 + fr) * LSTR + koff];
            afl[t] = *(const short8*)&Asl[(wm + t * 16 + fr) * LSTR + koff];
        }
#pragma unroll
        for (int t = 0; t < 4; t++) {
            bfh[t] = *(const short8*)&Bsh[(wn + t * 16 + fr) * LSTR + koff];
            bfl[t] = *(const short8*)&Bsl[(wn + t * 16 + fr) * LSTR + koff];
        }
#pragma unroll
        for (int mt = 0; mt < 2; mt++)
#pragma unroll
            for (int nt = 0; nt < 4; nt++) {
                acc[mt][nt] = __builtin_amdgcn_mfma_f32_16x16x32_bf16(afh[mt], bfh[nt], acc[mt][nt], 0, 0, 0);
                acc[mt][nt] = __builtin_amdgcn_mfma_f32_16x16x32_bf16(afh[mt], bfl[nt], acc[mt][nt], 0, 0, 0);
                acc[mt][nt] = __builtin_amdgcn_mfma_f32_16x16x32_bf16(afl[mt], bfh[nt], acc[mt][nt], 0, 0, 0);
            }
        __syncthreads();
    }

    const int row4 = (lane >> 4) * 4, coln = lane & 15;
#pragma unroll
    for (int mt = 0; mt < 2; mt++)
#pragma unroll
        for (int r = 0; r < 4; r++) {
            int m = bm + wm + mt * 16 + row4 + r;
            if (m < M) {
#pragma unroll
                for (int nt = 0; nt < 4; nt++) {
                    int n = bn + wn + nt * 16 + coln;
                    size_t idx = (size_t)m * HIDC + n;
                    float g = acc[mt][nt][r] + gWb[n] + gUb[n];
                    float alpha = 1.f / (1.f + expf(-g));
                    out[idx] = alpha * ht[idx] + (1.f - alpha) * prev[idx];
                }
            }
        }
}

// ---------------- CSR aggregation: one WAVE per row, ushort4 gathers, 4-deep unroll ----------------

__global__ __launch_bounds__(256) void csr_agg_kernel(
    const ushort* __restrict__ hm, const int* __restrict__ row_start,
    const int* __restrict__ csr_src, const float* __restrict__ csr_w,
    const float* __restrict__ dinv, const float* __restrict__ bias,
    float* __restrict__ outf, ushort* __restrict__ outb, int do_relu, int N)
{
    const int wave = threadIdx.x >> 6, lane = threadIdx.x & 63;
    const int i = blockIdx.x * 4 + wave;
    if (i >= N) return;
    const int c = lane * 4;

    const float di = dinv[i];
    const float s2 = di * di;
    ushort4 sv = *(const ushort4*)(hm + (size_t)i * HIDC + c);
    float a0 = s2 * bf2f(sv.x), a1 = s2 * bf2f(sv.y);
    float a2 = s2 * bf2f(sv.z), a3 = s2 * bf2f(sv.w);

    const int b0 = row_start[i], b1 = row_start[i + 1];
    int t = b0;
    for (; t + 4 <= b1; t += 4) {
        int   i0 = csr_src[t],     i1 = csr_src[t + 1];
        int   i2 = csr_src[t + 2], i3 = csr_src[t + 3];
        float w0 = csr_w[t],       w1 = csr_w[t + 1];
        float w2 = csr_w[t + 2],   w3 = csr_w[t + 3];
        ushort4 v0 = *(const ushort4*)(hm + (size_t)i0 * HIDC + c);
        ushort4 v1 = *(const ushort4*)(hm + (size_t)i1 * HIDC + c);
        ushort4 v2 = *(const ushort4*)(hm + (size_t)i2 * HIDC + c);
        ushort4 v3 = *(const ushort4*)(hm + (size_t)i3 * HIDC + c);
        a0 += w0 * bf2f(v0.x); a1 += w0 * bf2f(v0.y); a2 += w0 * bf2f(v0.z); a3 += w0 * bf2f(v0.w);
        a0 += w1 * bf2f(v1.x); a1 += w1 * bf2f(v1.y); a2 += w1 * bf2f(v1.z); a3 += w1 * bf2f(v1.w);
        a0 += w2 * bf2f(v2.x); a1 += w2 * bf2f(v2.y); a2 += w2 * bf2f(v2.z); a3 += w2 * bf2f(v2.w);
        a0 += w3 * bf2f(v3.x); a1 += w3 * bf2f(v3.y); a2 += w3 * bf2f(v3.z); a3 += w3 * bf2f(v3.w);
    }
    for (; t < b1; ++t) {
        int s_ = csr_src[t];
        float w = csr_w[t];
        ushort4 v = *(const ushort4*)(hm + (size_t)s_ * HIDC + c);
        a0 += w * bf2f(v.x); a1 += w * bf2f(v.y); a2 += w * bf2f(v.z); a3 += w * bf2f(v.w);
    }

    float4 bb = *(const float4*)(bias + c);
    a0 += bb.x; a1 += bb.y; a2 += bb.z; a3 += bb.w;
    if (do_relu) {
        a0 = fmaxf(a0, 0.f); a1 = fmaxf(a1, 0.f);
        a2 = fmaxf(a2, 0.f); a3 = fmaxf(a3, 0.f);
    }
    if (outb) {
        ushort4 o;
        o.x = f2bf_rne(a0); o.y = f2bf_rne(a1);
        o.z = f2bf_rne(a2); o.w = f2bf_rne(a3);
        *(ushort4*)(outb + (size_t)i * HIDC + c) = o;
    } else {
        *(float4*)(outf + (size_t)i * HIDC + c) = make_float4(a0, a1, a2, a3);
    }
}

// ---------------- launch ----------------

extern "C" void kernel_launch(void* const* d_in, const int* in_sizes, int n_in,
                              void* d_out, int out_size, void* d_ws, size_t ws_size,
                              hipStream_t stream) {
    const float* x    = (const float*)d_in[0];
    const int*   ei   = (const int*)d_in[1];
    const float* prev = (const float*)d_in[2];
    const float* W1   = (const float*)d_in[3];
    const float* b1   = (const float*)d_in[4];
    const float* W2   = (const float*)d_in[5];
    const float* b2   = (const float*)d_in[6];
    const float* gWw  = (const float*)d_in[7];
    const float* gWb  = (const float*)d_in[8];
    const float* gUw  = (const float*)d_in[9];
    const float* gUb  = (const float*)d_in[10];

    const int N = in_sizes[0] / HIDC;
    const int E = in_sizes[1] / 2;
    const int* src = ei;
    const int* dst = ei + E;

    float* out  = (float*)d_out;
    float* out1 = out;                       // h_tilde region (scratch first: h bf16)
    float* ht   = out + (size_t)N * HIDC;    // h_t region (f32)
    ushort* hbf = (ushort*)out1;             // bf16 h lives in out1 region until gate overwrites it

    // workspace layout (float units, 64-aligned chunks)
    float* ws = (float*)d_ws;
    size_t o = 0;
    auto take = [&](size_t n) { size_t r = o; o += (n + 63) & ~(size_t)63; return r; };
    float*  dinv    = ws + take(N);
    int*    degi    = (int*)(ws + take(N));
    int*    row_st  = (int*)(ws + take(N + 1));
    int*    cursor  = (int*)(ws + take(N + 1));
    int*    csr_src = (int*)(ws + take(E));
    float*  csr_w   = ws + take(E);
    ushort* Bt1     = (ushort*)(ws + take(256 * 256 / 2));
    ushort* Bt2     = (ushort*)(ws + take(256 * 256 / 2));
    ushort* Bth     = (ushort*)(ws + take(256 * 512 / 2));
    ushort* Btl     = (ushort*)(ws + take(256 * 512 / 2));
    ushort* hm      = (ushort*)(ws + take((size_t)N * HIDC / 2));

    const int nbN = (N + 255) / 256;
    const int nbE = (E + 255) / 256;
    dim3 ggrid((N + 127) / 128, 2);    // convs: BM=128
    dim3 ggridG((N + 63) / 64, 2);     // gate:  BM=64  (r4/r10-best)
    const int nbAgg = (N + 3) / 4;

    // ---- CSR build ----
    int* blocksum = (int*)csr_w;  // free until scatter_kernel
    fill_i_kernel<<<nbN, 256, 0, stream>>>(degi, 0, N);
    deg_kernel<<<nbE, 256, 0, stream>>>(dst, degi, E);
    scan_a_kernel<<<nbN, 256, 0, stream>>>(degi, row_st, blocksum, dinv, N);
    scan_b_kernel<<<1, 256, 0, stream>>>(blocksum, nbN);
    scan_c_kernel<<<nbN, 256, 0, stream>>>(row_st, cursor, blocksum, N);
    scatter_kernel<<<nbE, 256, 0, stream>>>(src, dst, dinv, cursor, csr_src, csr_w, E);

    // ---- weight prep (merged) ----
    prep_all_kernel<<<256, 256, 0, stream>>>(W1, W2, gWw, gUw, Bt1, Bt2, Bth, Btl);

    // ---- conv1 ----
    gemm_bf16_kernel<<<ggrid, 256, 0, stream>>>(x, Bt1, hm, N);
    csr_agg_kernel<<<nbAgg, 256, 0, stream>>>(hm, row_st, csr_src, csr_w, dinv, b1,
                                              nullptr, hbf, 1, N);

    // ---- conv2 (A already bf16) ----
    gemm_bf16A_kernel<<<ggrid, 256, 0, stream>>>(hbf, Bt2, hm, N);
    csr_agg_kernel<<<nbAgg, 256, 0, stream>>>(hm, row_st, csr_src, csr_w, dinv, b2,
                                              ht, nullptr, 0, N);

    // ---- gate (fused final; overwrites hbf region, which is fully consumed) ----
    gate_kernel<<<ggridG, 256, 0, stream>>>(ht, prev, Bth, Btl, gWb, gUb, out1, N);

    (void)n_in; (void)out_size; (void)ws_size;
}

// Round 14
// 507.122 us; speedup vs baseline: 1.0599x; 1.0599x over previous
//
#include <hip/hip_runtime.h>
#include <hip/hip_bf16.h>
#include <math.h>

#define HIDC 256
#define LSTR 40   // LDS row stride in ushorts: 80 B = 16B-aligned; stride=20 banks -> ~2-way (free per m136).

typedef short short8 __attribute__((ext_vector_type(8)));
typedef float f32x4 __attribute__((ext_vector_type(4)));

__device__ __forceinline__ ushort f2bf_rne(float f) {
    uint u = __float_as_uint(f);
    u += 0x7FFF + ((u >> 16) & 1);
    return (ushort)(u >> 16);
}
__device__ __forceinline__ float bf2f(ushort h) {
    return __uint_as_float(((uint)h) << 16);
}

// ---------------- small utility kernels ----------------

__global__ void fill_i_kernel(int* __restrict__ p, int v, int n) {
    int i = blockIdx.x * 256 + threadIdx.x;
    if (i < n) p[i] = v;
}

__global__ void deg_kernel(const int* __restrict__ dst, int* __restrict__ deg, int E) {
    int e = blockIdx.x * 256 + threadIdx.x;
    if (e < E) atomicAdd(&deg[dst[e]], 1);
}

// ---------------- 3-kernel exclusive scan (scan_a also emits dinv) ----------------

__device__ __forceinline__ int block_incl_scan(int v, int tid) {
#pragma unroll
    for (int off = 1; off < 64; off <<= 1) {
        int t = __shfl_up(v, off);
        if ((tid & 63) >= off) v += t;
    }
    __shared__ int wt[4];
    if ((tid & 63) == 63) wt[tid >> 6] = v;
    __syncthreads();
    int wid = tid >> 6;
    for (int w = 0; w < wid; w++) v += wt[w];
    __syncthreads();
    return v;
}

__global__ void scan_a_kernel(const int* __restrict__ deg, int* __restrict__ row_start,
                              int* __restrict__ blocksum, float* __restrict__ dinv, int N) {
    int tid = threadIdx.x;
    int i = blockIdx.x * 256 + tid;
    int v = (i < N) ? deg[i] : 0;
    int incl = block_incl_scan(v, tid);
    if (i < N) {
        row_start[i + 1] = incl;
        dinv[i] = rsqrtf((float)(v + 1));   // +1 = self-loop (folded rsqrt_kernel)
    }
    if (tid == 255) blocksum[blockIdx.x] = incl;
}

__global__ void scan_b_kernel(int* __restrict__ blocksum, int nb) {
    int tid = threadIdx.x;
    int v = (tid < nb) ? blocksum[tid] : 0;
    int incl = block_incl_scan(v, tid);
    if (tid < nb) blocksum[tid] = incl;
}

__global__ void scan_c_kernel(int* __restrict__ row_start, int* __restrict__ cursor,
                              const int* __restrict__ blocksum, int N) {
    int b = blockIdx.x;
    int i = b * 256 + threadIdx.x;
    int add = (b > 0) ? blocksum[b - 1] : 0;
    if (i < N) {
        int v = row_start[i + 1] + add;
        row_start[i + 1] = v;
        cursor[i + 1] = v;
    }
    if (b == 0 && threadIdx.x == 0) { row_start[0] = 0; cursor[0] = 0; }
}

__global__ void scatter_kernel(const int* __restrict__ src, const int* __restrict__ dst,
                               const float* __restrict__ dinv, int* __restrict__ cursor,
                               int* __restrict__ csr_src, float* __restrict__ csr_w, int E) {
    int e = blockIdx.x * 256 + threadIdx.x;
    if (e < E) {
        int s = src[e], d = dst[e];
        int pos = atomicAdd(&cursor[d], 1);
        csr_src[pos] = s;
        csr_w[pos] = dinv[s] * dinv[d];
    }
}

// ---------------- weight prep: single merged kernel ----------------
// Bt[n][k] = bf16(B[k][n]); gate: rows 0..255 <- gWw, 256..511 <- gUw, hi/lo split, [n][512k]

__global__ void prep_all_kernel(const float* __restrict__ W1, const float* __restrict__ W2,
                                const float* __restrict__ gWw, const float* __restrict__ gUw,
                                ushort* __restrict__ Bt1, ushort* __restrict__ Bt2,
                                ushort* __restrict__ Bth, ushort* __restrict__ Btl) {
    int n = blockIdx.x, k = threadIdx.x;
    Bt1[n * 256 + k] = f2bf_rne(W1[k * 256 + n]);
    Bt2[n * 256 + k] = f2bf_rne(W2[k * 256 + n]);
    float v1 = gWw[k * 256 + n];
    uint u1 = __float_as_uint(v1);
    Bth[n * 512 + k] = (ushort)(u1 >> 16);
    Btl[n * 512 + k] = f2bf_rne(v1 - __uint_as_float(u1 & 0xFFFF0000u));
    float v2 = gUw[k * 256 + n];
    uint u2 = __float_as_uint(v2);
    Bth[n * 512 + 256 + k] = (ushort)(u2 >> 16);
    Btl[n * 512 + 256 + k] = f2bf_rne(v2 - __uint_as_float(u2 & 0xFFFF0000u));
}

// ---------------- MFMA GEMM (r10-measured-best conv form): 128x128 tile, staged A+B, 2 barriers ----------------

__global__ __launch_bounds__(256, 4) void gemm_bf16_kernel(
    const float* __restrict__ A, const ushort* __restrict__ Bt,  // Bt: [256n][256k] bf16
    ushort* __restrict__ C, int M)
{
    __shared__ __align__(16) ushort As[128 * LSTR];
    __shared__ __align__(16) ushort Bs[128 * LSTR];
    const int tl = threadIdx.x;
    const int lane = tl & 63, wave = tl >> 6;
    const int wm = (wave & 1) * 64, wn = (wave >> 1) * 64;
    const int bm = blockIdx.x * 128, bn = blockIdx.y * 128;

    const int ar  = tl >> 1;          // A stage row
    const int akq = (tl & 1) * 16;    // A stage k base (16 floats)
    const bool aok = (bm + ar) < M;

    f32x4 acc[4][4] = {};

    for (int k0 = 0; k0 < 256; k0 += 32) {
        {   // A stage: f32 -> bf16 RNE
            const float* ap = A + (size_t)(bm + ar) * HIDC + k0 + akq;
#pragma unroll
            for (int j = 0; j < 4; j++) {
                float4 v = aok ? *(const float4*)(ap + 4 * j) : make_float4(0.f, 0.f, 0.f, 0.f);
                ushort4 h;
                h.x = f2bf_rne(v.x); h.y = f2bf_rne(v.y);
                h.z = f2bf_rne(v.z); h.w = f2bf_rne(v.w);
                *(ushort4*)&As[ar * LSTR + akq + 4 * j] = h;
            }
        }
        {   // B stage: copy 32 B
            const ushort* bp = Bt + (size_t)(bn + ar) * 256 + k0 + akq;
            *(uint4*)&Bs[ar * LSTR + akq]     = *(const uint4*)bp;
            *(uint4*)&Bs[ar * LSTR + akq + 8] = *(const uint4*)(bp + 8);
        }
        __syncthreads();
        const int fr = lane & 15, koff = (lane >> 4) * 8;
        short8 af[4], bfv[4];
#pragma unroll
        for (int t = 0; t < 4; t++) {
            af[t]  = *(const short8*)&As[(wm + t * 16 + fr) * LSTR + koff];
            bfv[t] = *(const short8*)&Bs[(wn + t * 16 + fr) * LSTR + koff];
        }
#pragma unroll
        for (int mt = 0; mt < 4; mt++)
#pragma unroll
            for (int nt = 0; nt < 4; nt++)
                acc[mt][nt] = __builtin_amdgcn_mfma_f32_16x16x32_bf16(af[mt], bfv[nt], acc[mt][nt], 0, 0, 0);
        __syncthreads();
    }

    // epilogue: C/D layout col=lane&15, row=(lane>>4)*4+reg  [m89-verified]
    const int row4 = (lane >> 4) * 4, coln = lane & 15;
#pragma unroll
    for (int mt = 0; mt < 4; mt++)
#pragma unroll
        for (int r = 0; r < 4; r++) {
            int m = bm + wm + mt * 16 + row4 + r;
            if (m < M) {
#pragma unroll
                for (int nt = 0; nt < 4; nt++) {
                    int n = bn + wn + nt * 16 + coln;
                    C[(size_t)m * HIDC + n] = f2bf_rne(acc[mt][nt][r]);
                }
            }
        }
}

// ---------------- MFMA GEMM, A already bf16 (pure-copy staging), r10 form ----------------

__global__ __launch_bounds__(256, 4) void gemm_bf16A_kernel(
    const ushort* __restrict__ A, const ushort* __restrict__ Bt,  // A: [M][256] bf16
    ushort* __restrict__ C, int M)
{
    __shared__ __align__(16) ushort As[128 * LSTR];
    __shared__ __align__(16) ushort Bs[128 * LSTR];
    const int tl = threadIdx.x;
    const int lane = tl & 63, wave = tl >> 6;
    const int wm = (wave & 1) * 64, wn = (wave >> 1) * 64;
    const int bm = blockIdx.x * 128, bn = blockIdx.y * 128;

    const int ar  = tl >> 1;
    const int akq = (tl & 1) * 16;
    const bool aok = (bm + ar) < M;

    f32x4 acc[4][4] = {};

    for (int k0 = 0; k0 < 256; k0 += 32) {
        {   // A stage: pure 16-ushort copy
            const ushort* ap = A + (size_t)(bm + ar) * HIDC + k0 + akq;
            uint4 z = make_uint4(0u, 0u, 0u, 0u);
            *(uint4*)&As[ar * LSTR + akq]     = aok ? *(const uint4*)ap       : z;
            *(uint4*)&As[ar * LSTR + akq + 8] = aok ? *(const uint4*)(ap + 8) : z;
        }
        {   // B stage
            const ushort* bp = Bt + (size_t)(bn + ar) * 256 + k0 + akq;
            *(uint4*)&Bs[ar * LSTR + akq]     = *(const uint4*)bp;
            *(uint4*)&Bs[ar * LSTR + akq + 8] = *(const uint4*)(bp + 8);
        }
        __syncthreads();
        const int fr = lane & 15, koff = (lane >> 4) * 8;
        short8 af[4], bfv[4];
#pragma unroll
        for (int t = 0; t < 4; t++) {
            af[t]  = *(const short8*)&As[(wm + t * 16 + fr) * LSTR + koff];
            bfv[t] = *(const short8*)&Bs[(wn + t * 16 + fr) * LSTR + koff];
        }
#pragma unroll
        for (int mt = 0; mt < 4; mt++)
#pragma unroll
            for (int nt = 0; nt < 4; nt++)
                acc[mt][nt] = __builtin_amdgcn_mfma_f32_16x16x32_bf16(af[mt], bfv[nt], acc[mt][nt], 0, 0, 0);
        __syncthreads();
    }

    const int row4 = (lane >> 4) * 4, coln = lane & 15;
#pragma unroll
    for (int mt = 0; mt < 4; mt++)
#pragma unroll
        for (int r = 0; r < 4; r++) {
            int m = bm + wm + mt * 16 + row4 + r;
            if (m < M) {
#pragma unroll
                for (int nt = 0; nt < 4; nt++) {
                    int n = bn + wn + nt * 16 + coln;
                    C[(size_t)m * HIDC + n] = f2bf_rne(acc[mt][nt][r]);
                }
            }
        }
}

// ---------------- gate GEMM (r10-measured-best, UNCHANGED): BM=64, staged hi/lo A + hi/lo B ----------------

__global__ __launch_bounds__(256, 4) void gate_kernel(
    const float* __restrict__ ht, const float* __restrict__ prev,
    const ushort* __restrict__ Bth, const ushort* __restrict__ Btl,  // [256n][512k]
    const float* __restrict__ gWb, const float* __restrict__ gUb,
    float* __restrict__ out, int M)
{
    __shared__ __align__(16) ushort Ash[64 * LSTR];
    __shared__ __align__(16) ushort Asl[64 * LSTR];
    __shared__ __align__(16) ushort Bsh[128 * LSTR];
    __shared__ __align__(16) ushort Bsl[128 * LSTR];
    const int tl = threadIdx.x;
    const int lane = tl & 63, wave = tl >> 6;
    const int wm = (wave & 1) * 32, wn = (wave >> 1) * 64;
    const int bm = blockIdx.x * 64, bn = blockIdx.y * 128;

    const int arA = tl >> 2;          // 0..63
    const int kqA = (tl & 3) * 8;     // 8 floats
    const int arB = tl >> 1;
    const int kqB = (tl & 1) * 16;
    const bool aok = (bm + arA) < M;

    f32x4 acc[2][4] = {};

    for (int k0 = 0; k0 < 512; k0 += 32) {
        {   // A stage: hi/lo split from ht (k<256) or prev, 8 elems/thread
            const float* srcA = (k0 < 256) ? ht : prev;
            const float* ap = srcA + (size_t)(bm + arA) * HIDC + (k0 & 255) + kqA;
            float4 v0 = aok ? *(const float4*)(ap)     : make_float4(0.f, 0.f, 0.f, 0.f);
            float4 v1 = aok ? *(const float4*)(ap + 4) : make_float4(0.f, 0.f, 0.f, 0.f);
            float vv[8] = {v0.x, v0.y, v0.z, v0.w, v1.x, v1.y, v1.z, v1.w};
            ushort hp[8], lp[8];
#pragma unroll
            for (int q = 0; q < 8; q++) {
                uint u = __float_as_uint(vv[q]);
                hp[q] = (ushort)(u >> 16);
                lp[q] = f2bf_rne(vv[q] - __uint_as_float(u & 0xFFFF0000u));
            }
            *(ushort4*)&Ash[arA * LSTR + kqA]     = make_ushort4(hp[0], hp[1], hp[2], hp[3]);
            *(ushort4*)&Ash[arA * LSTR + kqA + 4] = make_ushort4(hp[4], hp[5], hp[6], hp[7]);
            *(ushort4*)&Asl[arA * LSTR + kqA]     = make_ushort4(lp[0], lp[1], lp[2], lp[3]);
            *(ushort4*)&Asl[arA * LSTR + kqA + 4] = make_ushort4(lp[4], lp[5], lp[6], lp[7]);
        }
        {   // B stage
            const ushort* bph = Bth + (size_t)(bn + arB) * 512 + k0 + kqB;
            const ushort* bpl = Btl + (size_t)(bn + arB) * 512 + k0 + kqB;
            *(uint4*)&Bsh[arB * LSTR + kqB]     = *(const uint4*)bph;
            *(uint4*)&Bsh[arB * LSTR + kqB + 8] = *(const uint4*)(bph + 8);
            *(uint4*)&Bsl[arB * LSTR + kqB]     = *(const uint4*)bpl;
            *(uint4*)&Bsl[arB * LSTR + kqB + 8] = *(const uint4*)(bpl + 8);
        }
        __syncthreads();
        const int fr = lane & 15, koff = (lane >> 4) * 8;
        short8 afh[2], afl[2], bfh[4], bfl[4];
#pragma unroll
        for (int t = 0; t < 2; t++) {
            afh[t] = *(const short8*)&Ash[(wm + t * 16 + fr) * LSTR + koff];
            afl[t] = *(const short8*)&Asl[(wm + t * 16 + fr) * LSTR + koff];
        }
#pragma unroll
        for (int t = 0; t < 4; t++) {
            bfh[t] = *(const short8*)&Bsh[(wn + t * 16 + fr) * LSTR + koff];
            bfl[t] = *(const short8*)&Bsl[(wn + t * 16 + fr) * LSTR + koff];
        }
#pragma unroll
        for (int mt = 0; mt < 2; mt++)
#pragma unroll
            for (int nt = 0; nt < 4; nt++) {
                acc[mt][nt] = __builtin_amdgcn_mfma_f32_16x16x32_bf16(afh[mt], bfh[nt], acc[mt][nt], 0, 0, 0);
                acc[mt][nt] = __builtin_amdgcn_mfma_f32_16x16x32_bf16(afh[mt], bfl[nt], acc[mt][nt], 0, 0, 0);
                acc[mt][nt] = __builtin_amdgcn_mfma_f32_16x16x32_bf16(afl[mt], bfh[nt], acc[mt][nt], 0, 0, 0);
            }
        __syncthreads();
    }

    const int row4 = (lane >> 4) * 4, coln = lane & 15;
#pragma unroll
    for (int mt = 0; mt < 2; mt++)
#pragma unroll
        for (int r = 0; r < 4; r++) {
            int m = bm + wm + mt * 16 + row4 + r;
            if (m < M) {
#pragma unroll
                for (int nt = 0; nt < 4; nt++) {
                    int n = bn + wn + nt * 16 + coln;
                    size_t idx = (size_t)m * HIDC + n;
                    float g = acc[mt][nt][r] + gWb[n] + gUb[n];
                    float alpha = 1.f / (1.f + expf(-g));
                    out[idx] = alpha * ht[idx] + (1.f - alpha) * prev[idx];
                }
            }
        }
}

// ---------------- CSR aggregation: one WAVE per row, ushort4 gathers, 8-deep unroll ----------------
// Accumulation order stays strictly sequential in t -> bit-identical to 4-deep version.

__global__ __launch_bounds__(256) void csr_agg_kernel(
    const ushort* __restrict__ hm, const int* __restrict__ row_start,
    const int* __restrict__ csr_src, const float* __restrict__ csr_w,
    const float* __restrict__ dinv, const float* __restrict__ bias,
    float* __restrict__ outf, ushort* __restrict__ outb, int do_relu, int N)
{
    const int wave = threadIdx.x >> 6, lane = threadIdx.x & 63;
    const int i = blockIdx.x * 4 + wave;
    if (i >= N) return;
    const int c = lane * 4;

    const float di = dinv[i];
    const float s2 = di * di;
    ushort4 sv = *(const ushort4*)(hm + (size_t)i * HIDC + c);
    float a0 = s2 * bf2f(sv.x), a1 = s2 * bf2f(sv.y);
    float a2 = s2 * bf2f(sv.z), a3 = s2 * bf2f(sv.w);

    const int b0 = row_start[i], b1 = row_start[i + 1];
    int t = b0;
    for (; t + 8 <= b1; t += 8) {
        int   ix[8]; float wv[8]; ushort4 vv[8];
#pragma unroll
        for (int q = 0; q < 8; q++) { ix[q] = csr_src[t + q]; wv[q] = csr_w[t + q]; }
#pragma unroll
        for (int q = 0; q < 8; q++) vv[q] = *(const ushort4*)(hm + (size_t)ix[q] * HIDC + c);
#pragma unroll
        for (int q = 0; q < 8; q++) {
            a0 += wv[q] * bf2f(vv[q].x); a1 += wv[q] * bf2f(vv[q].y);
            a2 += wv[q] * bf2f(vv[q].z); a3 += wv[q] * bf2f(vv[q].w);
        }
    }
    for (; t + 4 <= b1; t += 4) {
        int   i0 = csr_src[t],     i1 = csr_src[t + 1];
        int   i2 = csr_src[t + 2], i3 = csr_src[t + 3];
        float w0 = csr_w[t],       w1 = csr_w[t + 1];
        float w2 = csr_w[t + 2],   w3 = csr_w[t + 3];
        ushort4 v0 = *(const ushort4*)(hm + (size_t)i0 * HIDC + c);
        ushort4 v1 = *(const ushort4*)(hm + (size_t)i1 * HIDC + c);
        ushort4 v2 = *(const ushort4*)(hm + (size_t)i2 * HIDC + c);
        ushort4 v3 = *(const ushort4*)(hm + (size_t)i3 * HIDC + c);
        a0 += w0 * bf2f(v0.x); a1 += w0 * bf2f(v0.y); a2 += w0 * bf2f(v0.z); a3 += w0 * bf2f(v0.w);
        a0 += w1 * bf2f(v1.x); a1 += w1 * bf2f(v1.y); a2 += w1 * bf2f(v1.z); a3 += w1 * bf2f(v1.w);
        a0 += w2 * bf2f(v2.x); a1 += w2 * bf2f(v2.y); a2 += w2 * bf2f(v2.z); a3 += w2 * bf2f(v2.w);
        a0 += w3 * bf2f(v3.x); a1 += w3 * bf2f(v3.y); a2 += w3 * bf2f(v3.z); a3 += w3 * bf2f(v3.w);
    }
    for (; t < b1; ++t) {
        int s_ = csr_src[t];
        float w = csr_w[t];
        ushort4 v = *(const ushort4*)(hm + (size_t)s_ * HIDC + c);
        a0 += w * bf2f(v.x); a1 += w * bf2f(v.y); a2 += w * bf2f(v.z); a3 += w * bf2f(v.w);
    }

    float4 bb = *(const float4*)(bias + c);
    a0 += bb.x; a1 += bb.y; a2 += bb.z; a3 += bb.w;
    if (do_relu) {
        a0 = fmaxf(a0, 0.f); a1 = fmaxf(a1, 0.f);
        a2 = fmaxf(a2, 0.f); a3 = fmaxf(a3, 0.f);
    }
    if (outb) {
        ushort4 o;
        o.x = f2bf_rne(a0); o.y = f2bf_rne(a1);
        o.z = f2bf_rne(a2); o.w = f2bf_rne(a3);
        *(ushort4*)(outb + (size_t)i * HIDC + c) = o;
    } else {
        *(float4*)(outf + (size_t)i * HIDC + c) = make_float4(a0, a1, a2, a3);
    }
}

// ---------------- launch ----------------

extern "C" void kernel_launch(void* const* d_in, const int* in_sizes, int n_in,
                              void* d_out, int out_size, void* d_ws, size_t ws_size,
                              hipStream_t stream) {
    const float* x    = (const float*)d_in[0];
    const int*   ei   = (const int*)d_in[1];
    const float* prev = (const float*)d_in[2];
    const float* W1   = (const float*)d_in[3];
    const float* b1   = (const float*)d_in[4];
    const float* W2   = (const float*)d_in[5];
    const float* b2   = (const float*)d_in[6];
    const float* gWw  = (const float*)d_in[7];
    const float* gWb  = (const float*)d_in[8];
    const float* gUw  = (const float*)d_in[9];
    const float* gUb  = (const float*)d_in[10];

    const int N = in_sizes[0] / HIDC;
    const int E = in_sizes[1] / 2;
    const int* src = ei;
    const int* dst = ei + E;

    float* out  = (float*)d_out;
    float* out1 = out;                       // h_tilde region (scratch first: h bf16)
    float* ht   = out + (size_t)N * HIDC;    // h_t region (f32)
    ushort* hbf = (ushort*)out1;             // bf16 h lives in out1 region until gate overwrites it

    // workspace layout (float units, 64-aligned chunks)
    float* ws = (float*)d_ws;
    size_t o = 0;
    auto take = [&](size_t n) { size_t r = o; o += (n + 63) & ~(size_t)63; return r; };
    float*  dinv    = ws + take(N);
    int*    degi    = (int*)(ws + take(N));
    int*    row_st  = (int*)(ws + take(N + 1));
    int*    cursor  = (int*)(ws + take(N + 1));
    int*    csr_src = (int*)(ws + take(E));
    float*  csr_w   = ws + take(E);
    ushort* Bt1     = (ushort*)(ws + take(256 * 256 / 2));
    ushort* Bt2     = (ushort*)(ws + take(256 * 256 / 2));
    ushort* Bth     = (ushort*)(ws + take(256 * 512 / 2));
    ushort* Btl     = (ushort*)(ws + take(256 * 512 / 2));
    ushort* hm      = (ushort*)(ws + take((size_t)N * HIDC / 2));

    const int nbN = (N + 255) / 256;
    const int nbE = (E + 255) / 256;
    dim3 ggrid((N + 127) / 128, 2);    // convs: BM=128 (r10-best)
    dim3 ggridG((N + 63) / 64, 2);     // gate:  BM=64  (r10-best)
    const int nbAgg = (N + 3) / 4;

    // ---- CSR build ----
    int* blocksum = (int*)csr_w;  // free until scatter_kernel
    fill_i_kernel<<<nbN, 256, 0, stream>>>(degi, 0, N);
    deg_kernel<<<nbE, 256, 0, stream>>>(dst, degi, E);
    scan_a_kernel<<<nbN, 256, 0, stream>>>(degi, row_st, blocksum, dinv, N);
    scan_b_kernel<<<1, 256, 0, stream>>>(blocksum, nbN);
    scan_c_kernel<<<nbN, 256, 0, stream>>>(row_st, cursor, blocksum, N);
    scatter_kernel<<<nbE, 256, 0, stream>>>(src, dst, dinv, cursor, csr_src, csr_w, E);

    // ---- weight prep (merged) ----
    prep_all_kernel<<<256, 256, 0, stream>>>(W1, W2, gWw, gUw, Bt1, Bt2, Bth, Btl);

    // ---- conv1 ----
    gemm_bf16_kernel<<<ggrid, 256, 0, stream>>>(x, Bt1, hm, N);
    csr_agg_kernel<<<nbAgg, 256, 0, stream>>>(hm, row_st, csr_src, csr_w, dinv, b1,
                                              nullptr, hbf, 1, N);

    // ---- conv2 (A already bf16) ----
    gemm_bf16A_kernel<<<ggrid, 256, 0, stream>>>(hbf, Bt2, hm, N);
    csr_agg_kernel<<<nbAgg, 256, 0, stream>>>(hm, row_st, csr_src, csr_w, dinv, b2,
                                              ht, nullptr, 0, N);

    // ---- gate (fused final; overwrites hbf region, which is fully consumed) ----
    gate_kernel<<<ggridG, 256, 0, stream>>>(ht, prev, Bth, Btl, gWb, gUb, out1, N);

    (void)n_in; (void)out_size; (void)ws_size;
}